// Round 8
// baseline (264.050 us; speedup 1.0000x reference)
//
#include <hip/hip_runtime.h>

#define DEVINL __device__ __forceinline__

DEVINL float gelu_exact(float x){ return 0.5f * x * (1.0f + erff(x * 0.70710678118654752f)); }
DEVINL float lrelu02(float x){ return x >= 0.0f ? x : 0.2f * x; }

// B=4 S=16 N=400 -> 64 graph batches, 25600 node-rows, 1600 sequences
#define NN    400
#define NROWS 25600
#define NSEQ  1600

// ws byte offsets (non-overlapping)
#define OFF_MASK 0u
#define OFF_HP1  160000u
#define OFF_ES1  1798400u
#define OFF_ED1  2208000u
#define OFF_X1   2617600u
#define OFF_HP2  4256000u
#define OFF_ES2  7532800u
#define OFF_ED2  7942400u
#define OFF_H2   8352000u

// K1: mask[i][j] = cos(emb_i, emb_j) > 0.5 ; block per i, thread per j
__global__ __launch_bounds__(512) void k_mask2(const float* __restrict__ emb,
                                               unsigned char* __restrict__ mask){
  int i = blockIdx.x, j = threadIdx.x;
  if (j >= NN) return;
  double si = 0.0, sj = 0.0, dp = 0.0;
  for (int k = 0; k < 16; k++){
    double a = (double)emb[i * 16 + k];
    double b = (double)emb[j * 16 + k];
    si += a * a; sj += b * b; dp += a * b;
  }
  double c = dp / (sqrt(fmax(si, 1e-12)) * sqrt(fmax(sj, 1e-12)));
  mask[i * NN + j] = (c > 0.5) ? (unsigned char)1 : (unsigned char)0;
}

// K2: hp1[row,c] = proj(x[row]) dot g1_w[:,c]; one THREAD per output element
__global__ __launch_bounds__(256) void k_pre1a(const float* __restrict__ x,
    const float* __restrict__ pw, const float* __restrict__ pb,
    const float* __restrict__ g1w, float* __restrict__ hp1){
  int idx = blockIdx.x * 256 + threadIdx.x;           // 409600
  if (idx >= NROWS * 16) return;
  int row = idx >> 4, c = idx & 15;
  float x0 = x[row*3+0], x1 = x[row*3+1], x2 = x[row*3+2];
  float a = 0.f;
  for (int k = 0; k < 16; k++){
    float h0k = pb[k] + x0 * pw[0*16+k] + x1 * pw[1*16+k] + x2 * pw[2*16+k];
    a += h0k * g1w[k*16 + c];
  }
  hp1[idx] = a;
}

// es/ed from hp: one THREAD per (row, head)
template<int F, int D>
__global__ __launch_bounds__(256) void k_esed(const float* __restrict__ hp,
    const float* __restrict__ asrc, const float* __restrict__ adst,
    float* __restrict__ es, float* __restrict__ ed){
  int idx = blockIdx.x * 256 + threadIdx.x;           // NROWS*4
  if (idx >= NROWS * 4) return;
  int row = idx >> 2, h = idx & 3;
  float s = 0.f, dsum = 0.f;
  for (int d = 0; d < D; d++){
    float v = hp[row*F + h*D + d];
    s    += v * asrc[h*D + d];
    dsum += v * adst[h*D + d];
  }
  es[idx] = s;
  ed[idx] = dsum;
}

// K4: hp2[row,c] = x1[row,:] dot g2_w[:,c]
__global__ __launch_bounds__(256) void k_pre2a(const float* __restrict__ x1,
    const float* __restrict__ g2w, float* __restrict__ hp2){
  int idx = blockIdx.x * 256 + threadIdx.x;           // 819200
  if (idx >= NROWS * 32) return;
  int row = idx >> 5, c = idx & 31;
  float a = 0.f;
  for (int k = 0; k < 16; k++) a += x1[row*16 + k] * g2w[k*32 + c];
  hp2[idx] = a;
}

// K3/K5: wave-parallel GAT. Block = 256 thr (4 waves), wave = one row.
// Lane = (h = lane>>4, js = lane&15); j strided by 16 within a 16-lane group.
// sh padded to stride F+4 (16B-aligned float4 reads, bank-spread).
template<int D, bool GELU>
__global__ __launch_bounds__(256) void k_gat_w(const float* __restrict__ hp,
    const float* __restrict__ es, const float* __restrict__ ed,
    const unsigned char* __restrict__ mask, const float* __restrict__ bias,
    float* __restrict__ outp){
  constexpr int F  = 4 * D;
  constexpr int PS = F + 4;                 // padded LDS stride (20 / 36 floats)
  __shared__ __align__(16) float sh[NN * PS];
  __shared__ float se[NN * 4];
  __shared__ float sb[F];
  const int tid = threadIdx.x;
  const int b = blockIdx.x >> 3, chunk = blockIdx.x & 7;
  const float* hb = hp + (size_t)b * NN * F;
  for (int idx = tid; idx < NN * F; idx += 256){
    int r = idx / F, c = idx - r * F;       // F is constexpr pow2 -> shifts
    sh[r * PS + c] = hb[idx];
  }
  const float* eb = es + (size_t)b * NN * 4;
  for (int idx = tid; idx < NN * 4; idx += 256) se[idx] = eb[idx];
  if (tid < F) sb[tid] = bias[tid];
  __syncthreads();
  const int w = tid >> 6, lane = tid & 63;
  const int h = lane >> 4, js = lane & 15;
  for (int li = w; li < 50; li += 4){
    const int i = chunk * 50 + li;
    const int row = b * NN + i;
    const float edh = ed[(size_t)row * 4 + h];
    const unsigned char* mr = mask + (size_t)i * NN;
    // pass 1: masked max of es[j][h] (lrelu monotone: m = lrelu(edh + max))
    float mx = -1e30f;
    for (int j = js; j < NN; j += 16)
      if (mr[j]) mx = fmaxf(mx, se[j*4 + h]);
    mx = fmaxf(mx, __shfl_xor(mx, 1));
    mx = fmaxf(mx, __shfl_xor(mx, 2));
    mx = fmaxf(mx, __shfl_xor(mx, 4));
    mx = fmaxf(mx, __shfl_xor(mx, 8));
    const float m = lrelu02(edh + mx);
    // pass 2: den + weighted accumulate (vector LDS reads)
    float den = 0.f;
    float acc[D];
    #pragma unroll
    for (int d = 0; d < D; d++) acc[d] = 0.f;
    for (int j = js; j < NN; j += 16){
      if (mr[j]){
        float pv = __expf(lrelu02(edh + se[j*4 + h]) - m);
        den += pv;
        const float4* vp = (const float4*)&sh[j*PS + h*D];
        float4 v0 = vp[0];
        acc[0] += pv * v0.x; acc[1] += pv * v0.y;
        acc[2] += pv * v0.z; acc[3] += pv * v0.w;
        if (D == 8){
          float4 v1 = vp[1];
          acc[4] += pv * v1.x; acc[5] += pv * v1.y;
          acc[6] += pv * v1.z; acc[7] += pv * v1.w;
        }
      }
    }
    #pragma unroll
    for (int mk = 1; mk <= 8; mk <<= 1){
      den += __shfl_xor(den, mk);
      #pragma unroll
      for (int d = 0; d < D; d++) acc[d] += __shfl_xor(acc[d], mk);
    }
    if (js < D){
      float num = 0.f;
      #pragma unroll
      for (int d = 0; d < D; d++) if (js == d) num = acc[d];   // static-index select
      float v = num / den + sb[h*D + js];
      if (GELU) v = gelu_exact(v);
      outp[(size_t)row * F + h*D + js] = v;
    }
  }
}

struct TW { const float* p[20]; };
// order: 0 wq,1 bq,2 wk,3 bk,4 wv,5 bv,6 wo,7 bo,8 ln1g,9 ln1b,
//        10 fw1,11 fb1,12 fw2,13 fb2,14 ln2g,15 ln2b,16 rw1,17 rb1,18 rw2,19 rb2

// K6: fused temporal transformer; f32 output
__global__ __launch_bounds__(512) void k_trans2(const float* __restrict__ h2, TW tw,
                                                float* __restrict__ out){
  __shared__ float Wq[1024], Wk[1024], Wv[1024], Wo[1024];
  __shared__ float Fw1[2048], Fw2[2048], Rw1[512];
  __shared__ float Bq[32], Bk[32], Bv[32], Bo[32], L1g[32], L1b[32];
  __shared__ float Fb1[64], Fb2[32], L2g[32], L2b[32], Rb1v[16], Rw2[16];
  __shared__ float Rb2s;
  __shared__ float T[512], QQ[512], KK[512], VV[512], SC[512], AT[512], X[512], Y[512];
  __shared__ float F2[1024];
  __shared__ float MX[32], DEN[32], M[32], RH[16];
  const int tid = threadIdx.x;
  const int p = blockIdx.x;
  for (int i = tid; i < 1024; i += 512){
    Wq[i] = tw.p[0][i]; Wk[i] = tw.p[2][i]; Wv[i] = tw.p[4][i]; Wo[i] = tw.p[6][i];
  }
  for (int i = tid; i < 2048; i += 512){ Fw1[i] = tw.p[10][i]; Fw2[i] = tw.p[12][i]; }
  if (tid < 512) Rw1[tid] = tw.p[16][tid];
  if (tid < 32){
    Bq[tid] = tw.p[1][tid]; Bk[tid] = tw.p[3][tid]; Bv[tid] = tw.p[5][tid]; Bo[tid] = tw.p[7][tid];
    L1g[tid] = tw.p[8][tid]; L1b[tid] = tw.p[9][tid]; Fb2[tid] = tw.p[13][tid];
    L2g[tid] = tw.p[14][tid]; L2b[tid] = tw.p[15][tid];
  }
  if (tid < 64) Fb1[tid] = tw.p[11][tid];
  if (tid < 16){ Rb1v[tid] = tw.p[17][tid]; Rw2[tid] = tw.p[18][tid]; }
  if (tid == 0) Rb2s = tw.p[19][0];
  const int s = tid >> 5, o = tid & 31;
  T[tid] = h2[(size_t)(p * 16 + s) * 32 + o];
  __syncthreads();
  {
    float aq = Bq[o], ak = Bk[o], av = Bv[o];
    for (int f = 0; f < 32; f++){
      float tv = T[s*32 + f];
      aq += tv * Wq[f*32 + o];
      ak += tv * Wk[f*32 + o];
      av += tv * Wv[f*32 + o];
    }
    QQ[tid] = aq; KK[tid] = ak; VV[tid] = av;
  }
  __syncthreads();
  {
    int h = tid >> 8, i = (tid >> 4) & 15, j = tid & 15;
    float d = 0.f;
    for (int dk = 0; dk < 16; dk++) d += QQ[i*32 + h*16 + dk] * KK[j*32 + h*16 + dk];
    SC[tid] = d * 0.25f;
  }
  __syncthreads();
  if (tid < 32){
    float mx = -1e30f;
    for (int j = 0; j < 16; j++) mx = fmaxf(mx, SC[tid*16 + j]);
    float den = 0.f;
    for (int j = 0; j < 16; j++) den += expf(SC[tid*16 + j] - mx);
    MX[tid] = mx; DEN[tid] = den;
  }
  __syncthreads();
  {
    int hi = tid >> 4;
    SC[tid] = expf(SC[tid] - MX[hi]) / DEN[hi];
  }
  __syncthreads();
  {
    int h = o >> 4;
    float a = 0.f;
    for (int j = 0; j < 16; j++) a += SC[(h*16 + s)*16 + j] * VV[j*32 + o];
    AT[tid] = a;
  }
  __syncthreads();
  {
    float v = Bo[o];
    for (int i2 = 0; i2 < 32; i2++) v += AT[s*32 + i2] * Wo[i2*32 + o];
    X[tid] = T[tid] + v;
  }
  __syncthreads();
  {
    float sm = 0.f, sq = 0.f;
    for (int f = 0; f < 32; f++){ float xv = X[s*32 + f]; sm += xv; sq += xv*xv; }
    float mean = sm * (1.f/32.f), var = sq * (1.f/32.f) - mean*mean;
    float inv = 1.0f / sqrtf(var + 1e-3f);
    T[tid] = (X[tid] - mean) * inv * L1g[o] + L1b[o];
  }
  __syncthreads();
  for (int c2 = tid; c2 < 1024; c2 += 512){
    int s3 = c2 >> 6, c = c2 & 63;
    float a = Fb1[c];
    for (int f = 0; f < 32; f++) a += T[s3*32 + f] * Fw1[f*64 + c];
    F2[c2] = gelu_exact(a);
  }
  __syncthreads();
  {
    float v = Fb2[o];
    for (int c = 0; c < 64; c++) v += F2[s*64 + c] * Fw2[c*32 + o];
    X[tid] = T[tid] + v;
  }
  __syncthreads();
  {
    float sm = 0.f, sq = 0.f;
    for (int f = 0; f < 32; f++){ float xv = X[s*32 + f]; sm += xv; sq += xv*xv; }
    float mean = sm * (1.f/32.f), var = sq * (1.f/32.f) - mean*mean;
    float inv = 1.0f / sqrtf(var + 1e-3f);
    Y[tid] = (X[tid] - mean) * inv * L2g[o] + L2b[o];
  }
  __syncthreads();
  if (tid < 32){
    float a = 0.f;
    for (int s2 = 0; s2 < 16; s2++) a += Y[s2*32 + tid];
    M[tid] = a * (1.f/16.f);
  }
  __syncthreads();
  if (tid < 16){
    float hid = Rb1v[tid];
    for (int o2 = 0; o2 < 32; o2++) hid += M[o2] * Rw1[o2*16 + tid];
    RH[tid] = gelu_exact(hid) * Rw2[tid];
  }
  __syncthreads();
  if (tid == 0){
    float a = Rb2s;
    for (int k = 0; k < 16; k++) a += RH[k];
    out[p] = a;
  }
}

extern "C" void kernel_launch(void* const* d_in, const int* in_sizes, int n_in,
                              void* d_out, int out_size, void* d_ws, size_t ws_size,
                              hipStream_t stream){
  const float* x    = (const float*)d_in[0];
  const float* adj  = (const float*)d_in[1];
  const float* pw   = (const float*)d_in[2];
  const float* pb   = (const float*)d_in[3];
  const float* g1w  = (const float*)d_in[4];
  const float* g1as = (const float*)d_in[5];
  const float* g1ad = (const float*)d_in[6];
  const float* g1b  = (const float*)d_in[7];
  const float* g2w  = (const float*)d_in[8];
  const float* g2as = (const float*)d_in[9];
  const float* g2ad = (const float*)d_in[10];
  const float* g2b  = (const float*)d_in[11];

  char* ws = (char*)d_ws;
  unsigned char* mask = (unsigned char*)(ws + OFF_MASK);
  float* hp1 = (float*)(ws + OFF_HP1);
  float* es1 = (float*)(ws + OFF_ES1);
  float* ed1 = (float*)(ws + OFF_ED1);
  float* x1  = (float*)(ws + OFF_X1);
  float* hp2 = (float*)(ws + OFF_HP2);
  float* es2 = (float*)(ws + OFF_ES2);
  float* ed2 = (float*)(ws + OFF_ED2);
  float* h2  = (float*)(ws + OFF_H2);

  TW tw;
  for (int t = 0; t < 20; t++) tw.p[t] = (const float*)d_in[12 + t];

  hipLaunchKernelGGL(k_mask2, dim3(NN), dim3(512), 0, stream, adj, mask);
  hipLaunchKernelGGL(k_pre1a, dim3(1600), dim3(256), 0, stream, x, pw, pb, g1w, hp1);
  hipLaunchKernelGGL((k_esed<16,4>), dim3(400), dim3(256), 0, stream, hp1, g1as, g1ad, es1, ed1);
  hipLaunchKernelGGL((k_gat_w<4, true>),  dim3(512), dim3(256), 0, stream, hp1, es1, ed1, mask, g1b, x1);
  hipLaunchKernelGGL(k_pre2a, dim3(3200), dim3(256), 0, stream, x1, g2w, hp2);
  hipLaunchKernelGGL((k_esed<32,8>), dim3(400), dim3(256), 0, stream, hp2, g2as, g2ad, es2, ed2);
  hipLaunchKernelGGL((k_gat_w<8, false>), dim3(512), dim3(256), 0, stream, hp2, es2, ed2, mask, g2b, h2);
  hipLaunchKernelGGL(k_trans2, dim3(NSEQ), dim3(512), 0, stream, h2, tw, (float*)d_out);
}

// Round 9
// 172.719 us; speedup vs baseline: 1.5288x; 1.5288x over previous
//
#include <hip/hip_runtime.h>

#define DEVINL __device__ __forceinline__

DEVINL float gelu_exact(float x){ return 0.5f * x * (1.0f + erff(x * 0.70710678118654752f)); }
DEVINL float lrelu02(float x){ return x >= 0.0f ? x : 0.2f * x; }

// B=4 S=16 N=400 -> 64 graph batches, 25600 node-rows, 1600 sequences
#define NN    400
#define NROWS 25600
#define NSEQ  1600

// ws byte offsets (non-overlapping)
#define OFF_MASK 0u
#define OFF_HP1  160000u
#define OFF_ES1  1798400u
#define OFF_ED1  2208000u
#define OFF_X1   2617600u
#define OFF_HP2  4256000u
#define OFF_ES2  7532800u
#define OFF_ED2  7942400u
#define OFF_H2   8352000u

// K1: mask[i][j] = cos(emb_i, emb_j) > 0.5 ; block per i, thread per j
__global__ __launch_bounds__(512) void k_mask2(const float* __restrict__ emb,
                                               unsigned char* __restrict__ mask){
  int i = blockIdx.x, j = threadIdx.x;
  if (j >= NN) return;
  double si = 0.0, sj = 0.0, dp = 0.0;
  for (int k = 0; k < 16; k++){
    double a = (double)emb[i * 16 + k];
    double b = (double)emb[j * 16 + k];
    si += a * a; sj += b * b; dp += a * b;
  }
  double c = dp / (sqrt(fmax(si, 1e-12)) * sqrt(fmax(sj, 1e-12)));
  mask[i * NN + j] = (c > 0.5) ? (unsigned char)1 : (unsigned char)0;
}

// K2: hp1[row,c] = proj(x[row]) dot g1_w[:,c]; one THREAD per output element
__global__ __launch_bounds__(256) void k_pre1a(const float* __restrict__ x,
    const float* __restrict__ pw, const float* __restrict__ pb,
    const float* __restrict__ g1w, float* __restrict__ hp1){
  int idx = blockIdx.x * 256 + threadIdx.x;           // 409600
  if (idx >= NROWS * 16) return;
  int row = idx >> 4, c = idx & 15;
  float x0 = x[row*3+0], x1 = x[row*3+1], x2 = x[row*3+2];
  float a = 0.f;
  for (int k = 0; k < 16; k++){
    float h0k = pb[k] + x0 * pw[0*16+k] + x1 * pw[1*16+k] + x2 * pw[2*16+k];
    a += h0k * g1w[k*16 + c];
  }
  hp1[idx] = a;
}

// es/ed from hp: one THREAD per (row, head)
template<int F, int D>
__global__ __launch_bounds__(256) void k_esed(const float* __restrict__ hp,
    const float* __restrict__ asrc, const float* __restrict__ adst,
    float* __restrict__ es, float* __restrict__ ed){
  int idx = blockIdx.x * 256 + threadIdx.x;           // NROWS*4
  if (idx >= NROWS * 4) return;
  int row = idx >> 2, h = idx & 3;
  float s = 0.f, dsum = 0.f;
  for (int d = 0; d < D; d++){
    float v = hp[row*F + h*D + d];
    s    += v * asrc[h*D + d];
    dsum += v * adst[h*D + d];
  }
  es[idx] = s;
  ed[idx] = dsum;
}

// K4: hp2[row,c] = x1[row,:] dot g2_w[:,c]
__global__ __launch_bounds__(256) void k_pre2a(const float* __restrict__ x1,
    const float* __restrict__ g2w, float* __restrict__ hp2){
  int idx = blockIdx.x * 256 + threadIdx.x;           // 819200
  if (idx >= NROWS * 32) return;
  int row = idx >> 5, c = idx & 31;
  float a = 0.f;
  for (int k = 0; k < 16; k++) a += x1[row*16 + k] * g2w[k*32 + c];
  hp2[idx] = a;
}

// K3/K5: wave-parallel GAT, branchless + mask-prefetch.
// Block = 256 thr (4 waves), wave = one row; lane = (h = lane>>4, js = lane&15).
template<int D, bool GELU>
__global__ __launch_bounds__(256) void k_gat_w(const float* __restrict__ hp,
    const float* __restrict__ es, const float* __restrict__ ed,
    const unsigned char* __restrict__ mask, const float* __restrict__ bias,
    float* __restrict__ outp){
  constexpr int F  = 4 * D;
  constexpr int PS = F + 4;                 // padded LDS stride (20 / 36 floats)
  constexpr int NT = NN / 16;               // 25 j-iterations per lane
  __shared__ __align__(16) float sh[NN * PS];
  __shared__ __align__(16) float se[NN * 4];
  __shared__ float sb[F];
  const int tid = threadIdx.x;
  const int b = blockIdx.x >> 3, chunk = blockIdx.x & 7;
  // vectorized staging: h tile (float4) into padded rows
  const float4* hb4 = (const float4*)(hp + (size_t)b * NN * F);
  for (int idx = tid; idx < NN * F / 4; idx += 256){
    int e0 = idx * 4;
    int r = e0 / F, c = e0 - r * F;         // F pow2 -> shifts
    *(float4*)&sh[r * PS + c] = hb4[idx];
  }
  const float4* eb4 = (const float4*)(es + (size_t)b * NN * 4);
  for (int idx = tid; idx < NN; idx += 256) *(float4*)&se[idx * 4] = eb4[idx];
  if (tid < F) sb[tid] = bias[tid];
  __syncthreads();
  const int w = tid >> 6, lane = tid & 63;
  const int h = lane >> 4, js = lane & 15;
  for (int li = w; li < 50; li += 4){
    const int i = chunk * 50 + li;
    const int row = b * NN + i;
    const float edh = ed[(size_t)row * 4 + h];
    const unsigned char* mr = mask + (size_t)i * NN;
    // prefetch all mask bytes for this row (independent loads, one latency)
    float msk[NT];
    #pragma unroll
    for (int t = 0; t < NT; t++) msk[t] = (float)mr[js + 16*t];
    // pass 1: masked max of es[j][h] (lrelu monotone)
    float mx = -1e30f;
    #pragma unroll
    for (int t = 0; t < NT; t++){
      float v = se[(js + 16*t)*4 + h];
      mx = fmaxf(mx, msk[t] > 0.5f ? v : -1e30f);
    }
    mx = fmaxf(mx, __shfl_xor(mx, 1));
    mx = fmaxf(mx, __shfl_xor(mx, 2));
    mx = fmaxf(mx, __shfl_xor(mx, 4));
    mx = fmaxf(mx, __shfl_xor(mx, 8));
    const float m = lrelu02(edh + mx);
    // pass 2: branchless den + weighted accumulate
    float den = 0.f;
    float acc[D];
    #pragma unroll
    for (int d = 0; d < D; d++) acc[d] = 0.f;
    #pragma unroll
    for (int t = 0; t < NT; t++){
      const int j = js + 16*t;
      float e = lrelu02(edh + se[j*4 + h]);
      float pv = msk[t] * __expf(e - m);    // 0 for masked-out (arg bounded)
      den += pv;
      const float4* vp = (const float4*)&sh[j*PS + h*D];
      float4 v0 = vp[0];
      acc[0] += pv * v0.x; acc[1] += pv * v0.y;
      acc[2] += pv * v0.z; acc[3] += pv * v0.w;
      if (D == 8){
        float4 v1 = vp[1];
        acc[4] += pv * v1.x; acc[5] += pv * v1.y;
        acc[6] += pv * v1.z; acc[7] += pv * v1.w;
      }
    }
    #pragma unroll
    for (int mk = 1; mk <= 8; mk <<= 1){
      den += __shfl_xor(den, mk);
      #pragma unroll
      for (int d = 0; d < D; d++) acc[d] += __shfl_xor(acc[d], mk);
    }
    if (js < D){
      float num = 0.f;
      #pragma unroll
      for (int d = 0; d < D; d++) if (js == d) num = acc[d];   // static-index select
      float v = num / den + sb[h*D + js];
      if (GELU) v = gelu_exact(v);
      outp[(size_t)row * F + h*D + js] = v;
    }
  }
}

struct TW { const float* p[20]; };
// order: 0 wq,1 bq,2 wk,3 bk,4 wv,5 bv,6 wo,7 bo,8 ln1g,9 ln1b,
//        10 fw1,11 fb1,12 fw2,13 fb2,14 ln2g,15 ln2b,16 rw1,17 rb1,18 rw2,19 rb2

// K6: fused temporal transformer; 4 sequences per block (weight staging amortized)
__global__ __launch_bounds__(512) void k_trans2(const float* __restrict__ h2, TW tw,
                                                float* __restrict__ out){
  __shared__ float Wq[1024], Wk[1024], Wv[1024], Wo[1024];
  __shared__ float Fw1[2048], Fw2[2048], Rw1[512];
  __shared__ float Bq[32], Bk[32], Bv[32], Bo[32], L1g[32], L1b[32];
  __shared__ float Fb1[64], Fb2[32], L2g[32], L2b[32], Rb1v[16], Rw2[16];
  __shared__ float Rb2s;
  __shared__ float T[512], QQ[512], KK[512], VV[512], SC[512], AT[512], X[512], Y[512];
  __shared__ float F2[1024];
  __shared__ float MX[32], DEN[32], M[32], RH[16];
  const int tid = threadIdx.x;
  for (int i = tid; i < 1024; i += 512){
    Wq[i] = tw.p[0][i]; Wk[i] = tw.p[2][i]; Wv[i] = tw.p[4][i]; Wo[i] = tw.p[6][i];
  }
  for (int i = tid; i < 2048; i += 512){ Fw1[i] = tw.p[10][i]; Fw2[i] = tw.p[12][i]; }
  if (tid < 512) Rw1[tid] = tw.p[16][tid];
  if (tid < 32){
    Bq[tid] = tw.p[1][tid]; Bk[tid] = tw.p[3][tid]; Bv[tid] = tw.p[5][tid]; Bo[tid] = tw.p[7][tid];
    L1g[tid] = tw.p[8][tid]; L1b[tid] = tw.p[9][tid]; Fb2[tid] = tw.p[13][tid];
    L2g[tid] = tw.p[14][tid]; L2b[tid] = tw.p[15][tid];
  }
  if (tid < 64) Fb1[tid] = tw.p[11][tid];
  if (tid < 16){ Rb1v[tid] = tw.p[17][tid]; Rw2[tid] = tw.p[18][tid]; }
  if (tid == 0) Rb2s = tw.p[19][0];
  const int s = tid >> 5, o = tid & 31;
  for (int pp = 0; pp < 4; pp++){
    const int p = blockIdx.x * 4 + pp;
    __syncthreads();   // covers W staging (pp=0) and prev-iteration reads
    T[tid] = h2[(size_t)(p * 16 + s) * 32 + o];
    __syncthreads();
    {
      float aq = Bq[o], ak = Bk[o], av = Bv[o];
      for (int f = 0; f < 32; f++){
        float tv = T[s*32 + f];
        aq += tv * Wq[f*32 + o];
        ak += tv * Wk[f*32 + o];
        av += tv * Wv[f*32 + o];
      }
      QQ[tid] = aq; KK[tid] = ak; VV[tid] = av;
    }
    __syncthreads();
    {
      int h = tid >> 8, i = (tid >> 4) & 15, j = tid & 15;
      float d = 0.f;
      for (int dk = 0; dk < 16; dk++) d += QQ[i*32 + h*16 + dk] * KK[j*32 + h*16 + dk];
      SC[tid] = d * 0.25f;
    }
    __syncthreads();
    if (tid < 32){
      float mx = -1e30f;
      for (int j = 0; j < 16; j++) mx = fmaxf(mx, SC[tid*16 + j]);
      float den = 0.f;
      for (int j = 0; j < 16; j++) den += expf(SC[tid*16 + j] - mx);
      MX[tid] = mx; DEN[tid] = den;
    }
    __syncthreads();
    {
      int hi = tid >> 4;
      SC[tid] = expf(SC[tid] - MX[hi]) / DEN[hi];
    }
    __syncthreads();
    {
      int h = o >> 4;
      float a = 0.f;
      for (int j = 0; j < 16; j++) a += SC[(h*16 + s)*16 + j] * VV[j*32 + o];
      AT[tid] = a;
    }
    __syncthreads();
    {
      float v = Bo[o];
      for (int i2 = 0; i2 < 32; i2++) v += AT[s*32 + i2] * Wo[i2*32 + o];
      X[tid] = T[tid] + v;
    }
    __syncthreads();
    {
      float sm = 0.f, sq = 0.f;
      for (int f = 0; f < 32; f++){ float xv = X[s*32 + f]; sm += xv; sq += xv*xv; }
      float mean = sm * (1.f/32.f), var = sq * (1.f/32.f) - mean*mean;
      float inv = 1.0f / sqrtf(var + 1e-3f);
      T[tid] = (X[tid] - mean) * inv * L1g[o] + L1b[o];
    }
    __syncthreads();
    for (int c2 = tid; c2 < 1024; c2 += 512){
      int s3 = c2 >> 6, c = c2 & 63;
      float a = Fb1[c];
      for (int f = 0; f < 32; f++) a += T[s3*32 + f] * Fw1[f*64 + c];
      F2[c2] = gelu_exact(a);
    }
    __syncthreads();
    {
      float v = Fb2[o];
      for (int c = 0; c < 64; c++) v += F2[s*64 + c] * Fw2[c*32 + o];
      X[tid] = T[tid] + v;
    }
    __syncthreads();
    {
      float sm = 0.f, sq = 0.f;
      for (int f = 0; f < 32; f++){ float xv = X[s*32 + f]; sm += xv; sq += xv*xv; }
      float mean = sm * (1.f/32.f), var = sq * (1.f/32.f) - mean*mean;
      float inv = 1.0f / sqrtf(var + 1e-3f);
      Y[tid] = (X[tid] - mean) * inv * L2g[o] + L2b[o];
    }
    __syncthreads();
    if (tid < 32){
      float a = 0.f;
      for (int s2 = 0; s2 < 16; s2++) a += Y[s2*32 + tid];
      M[tid] = a * (1.f/16.f);
    }
    __syncthreads();
    if (tid < 16){
      float hid = Rb1v[tid];
      for (int o2 = 0; o2 < 32; o2++) hid += M[o2] * Rw1[o2*16 + tid];
      RH[tid] = gelu_exact(hid) * Rw2[tid];
    }
    __syncthreads();
    if (tid == 0){
      float a = Rb2s;
      for (int k = 0; k < 16; k++) a += RH[k];
      out[p] = a;
    }
  }
}

extern "C" void kernel_launch(void* const* d_in, const int* in_sizes, int n_in,
                              void* d_out, int out_size, void* d_ws, size_t ws_size,
                              hipStream_t stream){
  const float* x    = (const float*)d_in[0];
  const float* adj  = (const float*)d_in[1];
  const float* pw   = (const float*)d_in[2];
  const float* pb   = (const float*)d_in[3];
  const float* g1w  = (const float*)d_in[4];
  const float* g1as = (const float*)d_in[5];
  const float* g1ad = (const float*)d_in[6];
  const float* g1b  = (const float*)d_in[7];
  const float* g2w  = (const float*)d_in[8];
  const float* g2as = (const float*)d_in[9];
  const float* g2ad = (const float*)d_in[10];
  const float* g2b  = (const float*)d_in[11];

  char* ws = (char*)d_ws;
  unsigned char* mask = (unsigned char*)(ws + OFF_MASK);
  float* hp1 = (float*)(ws + OFF_HP1);
  float* es1 = (float*)(ws + OFF_ES1);
  float* ed1 = (float*)(ws + OFF_ED1);
  float* x1  = (float*)(ws + OFF_X1);
  float* hp2 = (float*)(ws + OFF_HP2);
  float* es2 = (float*)(ws + OFF_ES2);
  float* ed2 = (float*)(ws + OFF_ED2);
  float* h2  = (float*)(ws + OFF_H2);

  TW tw;
  for (int t = 0; t < 20; t++) tw.p[t] = (const float*)d_in[12 + t];

  hipLaunchKernelGGL(k_mask2, dim3(NN), dim3(512), 0, stream, adj, mask);
  hipLaunchKernelGGL(k_pre1a, dim3(1600), dim3(256), 0, stream, x, pw, pb, g1w, hp1);
  hipLaunchKernelGGL((k_esed<16,4>), dim3(400), dim3(256), 0, stream, hp1, g1as, g1ad, es1, ed1);
  hipLaunchKernelGGL((k_gat_w<4, true>),  dim3(512), dim3(256), 0, stream, hp1, es1, ed1, mask, g1b, x1);
  hipLaunchKernelGGL(k_pre2a, dim3(3200), dim3(256), 0, stream, x1, g2w, hp2);
  hipLaunchKernelGGL((k_esed<32,8>), dim3(400), dim3(256), 0, stream, hp2, g2as, g2ad, es2, ed2);
  hipLaunchKernelGGL((k_gat_w<8, false>), dim3(512), dim3(256), 0, stream, hp2, es2, ed2, mask, g2b, h2);
  hipLaunchKernelGGL(k_trans2, dim3(NSEQ/4), dim3(512), 0, stream, h2, tw, (float*)d_out);
}

// Round 10
// 92.212 us; speedup vs baseline: 2.8635x; 1.8731x over previous
//
#include <hip/hip_runtime.h>

#define DEVINL __device__ __forceinline__

DEVINL float gelu_exact(float x){ return 0.5f * x * (1.0f + erff(x * 0.70710678118654752f)); }
DEVINL float lrelu02(float x){ return x >= 0.0f ? x : 0.2f * x; }

// B=4 S=16 N=400 -> 64 graph batches, 25600 node-rows, 1600 sequences
#define NN    400
#define NROWS 25600
#define NSEQ  1600

// ws byte offsets; peak 8,513,600 (h2 overlaps dead hp1/es1/ed1/x1)
#define OFF_NBR  0u          /* u16 nlist[400][400] = 320000 */
#define OFF_CNT  320000u     /* int cnt[400] = 1600 */
#define OFF_HP1  321600u     /* 1638400 */
#define OFF_ES1  1960000u    /* 409600 */
#define OFF_ED1  2369600u    /* 409600 */
#define OFF_X1   2779200u    /* 1638400 */
#define OFF_HP2  4417600u    /* 3276800 */
#define OFF_ES2  7694400u    /* 409600 */
#define OFF_ED2  8104000u    /* 409600 */
#define OFF_H2   321600u     /* reuses hp1..x1 region (dead by gat2); 3276800 */

// K1: sparse neighbor lists from cosine(adj_embed) > 0.5.
// One wave per row i; ordered ballot-compaction => deterministic, j-ascending.
__global__ __launch_bounds__(64) void k_nbr(const float* __restrict__ emb,
                                            unsigned short* __restrict__ nlist,
                                            int* __restrict__ cnt){
  const int i = blockIdx.x;
  const int lane = threadIdx.x;
  double ai[16];
  double si = 0.0;
  #pragma unroll
  for (int k = 0; k < 16; k++){ ai[k] = (double)emb[i*16 + k]; si += ai[k]*ai[k]; }
  const double rni = 1.0 / sqrt(fmax(si, 1e-12));
  int base = 0;
  #pragma unroll
  for (int t = 0; t < 7; t++){
    const int j = t*64 + lane;
    bool valid = false;
    if (j < NN){
      double sj = 0.0, dp = 0.0;
      #pragma unroll
      for (int k = 0; k < 16; k++){
        double bv = (double)emb[j*16 + k];
        sj += bv*bv; dp += ai[k]*bv;
      }
      double c = dp * rni / sqrt(fmax(sj, 1e-12));
      valid = (c > 0.5);
    }
    unsigned long long bal = __ballot(valid);
    int pre = __popcll(bal & ((1ull << lane) - 1ull));
    if (valid) nlist[i*NN + base + pre] = (unsigned short)j;
    base += (int)__popcll(bal);
  }
  if (lane == 0) cnt[i] = base;
}

// K2: hp1[row,c] = proj(x[row]) dot g1_w[:,c]; one THREAD per output element
__global__ __launch_bounds__(256) void k_pre1a(const float* __restrict__ x,
    const float* __restrict__ pw, const float* __restrict__ pb,
    const float* __restrict__ g1w, float* __restrict__ hp1){
  int idx = blockIdx.x * 256 + threadIdx.x;           // 409600
  if (idx >= NROWS * 16) return;
  int row = idx >> 4, c = idx & 15;
  float x0 = x[row*3+0], x1 = x[row*3+1], x2 = x[row*3+2];
  float a = 0.f;
  for (int k = 0; k < 16; k++){
    float h0k = pb[k] + x0 * pw[0*16+k] + x1 * pw[1*16+k] + x2 * pw[2*16+k];
    a += h0k * g1w[k*16 + c];
  }
  hp1[idx] = a;
}

// es/ed from hp: one THREAD per (row, head)
template<int F, int D>
__global__ __launch_bounds__(256) void k_esed(const float* __restrict__ hp,
    const float* __restrict__ asrc, const float* __restrict__ adst,
    float* __restrict__ es, float* __restrict__ ed){
  int idx = blockIdx.x * 256 + threadIdx.x;           // NROWS*4
  if (idx >= NROWS * 4) return;
  int row = idx >> 2, h = idx & 3;
  float s = 0.f, dsum = 0.f;
  for (int d = 0; d < D; d++){
    float v = hp[row*F + h*D + d];
    s    += v * asrc[h*D + d];
    dsum += v * adst[h*D + d];
  }
  es[idx] = s;
  ed[idx] = dsum;
}

// K4: hp2[row,c] = x1[row,:] dot g2_w[:,c]
__global__ __launch_bounds__(256) void k_pre2a(const float* __restrict__ x1,
    const float* __restrict__ g2w, float* __restrict__ hp2){
  int idx = blockIdx.x * 256 + threadIdx.x;           // 819200
  if (idx >= NROWS * 32) return;
  int row = idx >> 5, c = idx & 31;
  float a = 0.f;
  for (int k = 0; k < 16; k++) a += x1[row*16 + k] * g2w[k*32 + c];
  hp2[idx] = a;
}

// K3/K5: SPARSE GAT. One THREAD per (row, head); neighbor list ~10 entries avg.
// No LDS; chunked-by-8 branchless loads (padded index + weight-0 tail) for ILP.
template<int D, bool GELU>
__global__ __launch_bounds__(256) void k_gat_s(const float* __restrict__ hp,
    const float* __restrict__ es, const float* __restrict__ ed,
    const unsigned short* __restrict__ nlist, const int* __restrict__ cnt,
    const float* __restrict__ bias, float* __restrict__ outp){
  constexpr int F = 4 * D;
  int idx = blockIdx.x * 256 + threadIdx.x;           // NROWS*4 = 102400
  if (idx >= NROWS * 4) return;
  const int row = idx >> 2, h = idx & 3;
  const int b = row / NN;
  const int i = row - b * NN;
  const int n = cnt[i];
  const unsigned short* nl = nlist + i * NN;
  const float* esb = es + (size_t)b * NN * 4;
  const float* hpb = hp + (size_t)b * NN * F;
  const float edh = ed[(size_t)row * 4 + h];
  // pass 1: max of es over neighbors (lrelu monotone => one lrelu at the end)
  float mx = -1e30f;
  for (int k0 = 0; k0 < n; k0 += 8){
    int jj[8]; float wv[8];
    #pragma unroll
    for (int u = 0; u < 8; u++){
      int kk = k0 + u;
      jj[u] = (int)nl[kk < n ? kk : n - 1];
      wv[u] = (kk < n) ? 1.f : 0.f;
    }
    #pragma unroll
    for (int u = 0; u < 8; u++){
      float v = esb[jj[u]*4 + h];
      mx = fmaxf(mx, wv[u] > 0.5f ? v : -1e30f);
    }
  }
  const float m = lrelu02(edh + mx);
  // pass 2: denom + weighted accumulate
  float den = 0.f;
  float acc[D];
  #pragma unroll
  for (int d = 0; d < D; d++) acc[d] = 0.f;
  for (int k0 = 0; k0 < n; k0 += 8){
    int jj[8]; float wv[8], ev[8];
    #pragma unroll
    for (int u = 0; u < 8; u++){
      int kk = k0 + u;
      jj[u] = (int)nl[kk < n ? kk : n - 1];
      wv[u] = (kk < n) ? 1.f : 0.f;
    }
    #pragma unroll
    for (int u = 0; u < 8; u++) ev[u] = esb[jj[u]*4 + h];
    #pragma unroll
    for (int u = 0; u < 8; u++){
      float pv = wv[u] * __expf(lrelu02(edh + ev[u]) - m);
      den += pv;
      const float4* vp = (const float4*)(hpb + (size_t)jj[u]*F + h*D);
      float4 v0 = vp[0];
      acc[0] += pv * v0.x; acc[1] += pv * v0.y;
      acc[2] += pv * v0.z; acc[3] += pv * v0.w;
      if (D == 8){
        float4 v1 = vp[1];
        acc[4] += pv * v1.x; acc[5] += pv * v1.y;
        acc[6] += pv * v1.z; acc[7] += pv * v1.w;
      }
    }
  }
  const float invd = 1.0f / den;
  float* op = outp + (size_t)row * F + h * D;
  #pragma unroll
  for (int d = 0; d < D; d++){
    float v = acc[d] * invd + bias[h*D + d];
    if (GELU) v = gelu_exact(v);
    op[d] = v;
  }
}

struct TW { const float* p[20]; };
// order: 0 wq,1 bq,2 wk,3 bk,4 wv,5 bv,6 wo,7 bo,8 ln1g,9 ln1b,
//        10 fw1,11 fb1,12 fw2,13 fb2,14 ln2g,15 ln2b,16 rw1,17 rb1,18 rw2,19 rb2

// K6: fused temporal transformer; 4 sequences per block
__global__ __launch_bounds__(512) void k_trans2(const float* __restrict__ h2, TW tw,
                                                float* __restrict__ out){
  __shared__ float Wq[1024], Wk[1024], Wv[1024], Wo[1024];
  __shared__ float Fw1[2048], Fw2[2048], Rw1[512];
  __shared__ float Bq[32], Bk[32], Bv[32], Bo[32], L1g[32], L1b[32];
  __shared__ float Fb1[64], Fb2[32], L2g[32], L2b[32], Rb1v[16], Rw2[16];
  __shared__ float Rb2s;
  __shared__ float T[512], QQ[512], KK[512], VV[512], SC[512], AT[512], X[512], Y[512];
  __shared__ float F2[1024];
  __shared__ float MX[32], DEN[32], M[32], RH[16];
  const int tid = threadIdx.x;
  for (int i = tid; i < 1024; i += 512){
    Wq[i] = tw.p[0][i]; Wk[i] = tw.p[2][i]; Wv[i] = tw.p[4][i]; Wo[i] = tw.p[6][i];
  }
  for (int i = tid; i < 2048; i += 512){ Fw1[i] = tw.p[10][i]; Fw2[i] = tw.p[12][i]; }
  if (tid < 512) Rw1[tid] = tw.p[16][tid];
  if (tid < 32){
    Bq[tid] = tw.p[1][tid]; Bk[tid] = tw.p[3][tid]; Bv[tid] = tw.p[5][tid]; Bo[tid] = tw.p[7][tid];
    L1g[tid] = tw.p[8][tid]; L1b[tid] = tw.p[9][tid]; Fb2[tid] = tw.p[13][tid];
    L2g[tid] = tw.p[14][tid]; L2b[tid] = tw.p[15][tid];
  }
  if (tid < 64) Fb1[tid] = tw.p[11][tid];
  if (tid < 16){ Rb1v[tid] = tw.p[17][tid]; Rw2[tid] = tw.p[18][tid]; }
  if (tid == 0) Rb2s = tw.p[19][0];
  const int s = tid >> 5, o = tid & 31;
  for (int pp = 0; pp < 4; pp++){
    const int p = blockIdx.x * 4 + pp;
    __syncthreads();   // covers W staging (pp=0) and prev-iteration reads
    T[tid] = h2[(size_t)(p * 16 + s) * 32 + o];
    __syncthreads();
    {
      float aq = Bq[o], ak = Bk[o], av = Bv[o];
      for (int f = 0; f < 32; f++){
        float tv = T[s*32 + f];
        aq += tv * Wq[f*32 + o];
        ak += tv * Wk[f*32 + o];
        av += tv * Wv[f*32 + o];
      }
      QQ[tid] = aq; KK[tid] = ak; VV[tid] = av;
    }
    __syncthreads();
    {
      int h = tid >> 8, i = (tid >> 4) & 15, j = tid & 15;
      float d = 0.f;
      for (int dk = 0; dk < 16; dk++) d += QQ[i*32 + h*16 + dk] * KK[j*32 + h*16 + dk];
      SC[tid] = d * 0.25f;
    }
    __syncthreads();
    if (tid < 32){
      float mx = -1e30f;
      for (int j = 0; j < 16; j++) mx = fmaxf(mx, SC[tid*16 + j]);
      float den = 0.f;
      for (int j = 0; j < 16; j++) den += expf(SC[tid*16 + j] - mx);
      MX[tid] = mx; DEN[tid] = den;
    }
    __syncthreads();
    {
      int hi = tid >> 4;
      SC[tid] = expf(SC[tid] - MX[hi]) / DEN[hi];
    }
    __syncthreads();
    {
      int h = o >> 4;
      float a = 0.f;
      for (int j = 0; j < 16; j++) a += SC[(h*16 + s)*16 + j] * VV[j*32 + o];
      AT[tid] = a;
    }
    __syncthreads();
    {
      float v = Bo[o];
      for (int i2 = 0; i2 < 32; i2++) v += AT[s*32 + i2] * Wo[i2*32 + o];
      X[tid] = T[tid] + v;
    }
    __syncthreads();
    {
      float sm = 0.f, sq = 0.f;
      for (int f = 0; f < 32; f++){ float xv = X[s*32 + f]; sm += xv; sq += xv*xv; }
      float mean = sm * (1.f/32.f), var = sq * (1.f/32.f) - mean*mean;
      float inv = 1.0f / sqrtf(var + 1e-3f);
      T[tid] = (X[tid] - mean) * inv * L1g[o] + L1b[o];
    }
    __syncthreads();
    for (int c2 = tid; c2 < 1024; c2 += 512){
      int s3 = c2 >> 6, c = c2 & 63;
      float a = Fb1[c];
      for (int f = 0; f < 32; f++) a += T[s3*32 + f] * Fw1[f*64 + c];
      F2[c2] = gelu_exact(a);
    }
    __syncthreads();
    {
      float v = Fb2[o];
      for (int c = 0; c < 64; c++) v += F2[s*64 + c] * Fw2[c*32 + o];
      X[tid] = T[tid] + v;
    }
    __syncthreads();
    {
      float sm = 0.f, sq = 0.f;
      for (int f = 0; f < 32; f++){ float xv = X[s*32 + f]; sm += xv; sq += xv*xv; }
      float mean = sm * (1.f/32.f), var = sq * (1.f/32.f) - mean*mean;
      float inv = 1.0f / sqrtf(var + 1e-3f);
      Y[tid] = (X[tid] - mean) * inv * L2g[o] + L2b[o];
    }
    __syncthreads();
    if (tid < 32){
      float a = 0.f;
      for (int s2 = 0; s2 < 16; s2++) a += Y[s2*32 + tid];
      M[tid] = a * (1.f/16.f);
    }
    __syncthreads();
    if (tid < 16){
      float hid = Rb1v[tid];
      for (int o2 = 0; o2 < 32; o2++) hid += M[o2] * Rw1[o2*16 + tid];
      RH[tid] = gelu_exact(hid) * Rw2[tid];
    }
    __syncthreads();
    if (tid == 0){
      float a = Rb2s;
      for (int k = 0; k < 16; k++) a += RH[k];
      out[p] = a;
    }
  }
}

extern "C" void kernel_launch(void* const* d_in, const int* in_sizes, int n_in,
                              void* d_out, int out_size, void* d_ws, size_t ws_size,
                              hipStream_t stream){
  const float* x    = (const float*)d_in[0];
  const float* adj  = (const float*)d_in[1];
  const float* pw   = (const float*)d_in[2];
  const float* pb   = (const float*)d_in[3];
  const float* g1w  = (const float*)d_in[4];
  const float* g1as = (const float*)d_in[5];
  const float* g1ad = (const float*)d_in[6];
  const float* g1b  = (const float*)d_in[7];
  const float* g2w  = (const float*)d_in[8];
  const float* g2as = (const float*)d_in[9];
  const float* g2ad = (const float*)d_in[10];
  const float* g2b  = (const float*)d_in[11];

  char* ws = (char*)d_ws;
  unsigned short* nlist = (unsigned short*)(ws + OFF_NBR);
  int*   cnt = (int*)(ws + OFF_CNT);
  float* hp1 = (float*)(ws + OFF_HP1);
  float* es1 = (float*)(ws + OFF_ES1);
  float* ed1 = (float*)(ws + OFF_ED1);
  float* x1  = (float*)(ws + OFF_X1);
  float* hp2 = (float*)(ws + OFF_HP2);
  float* es2 = (float*)(ws + OFF_ES2);
  float* ed2 = (float*)(ws + OFF_ED2);
  float* h2  = (float*)(ws + OFF_H2);   // overlaps hp1..x1 (dead by gat2)

  TW tw;
  for (int t = 0; t < 20; t++) tw.p[t] = (const float*)d_in[12 + t];

  hipLaunchKernelGGL(k_nbr,   dim3(NN), dim3(64), 0, stream, adj, nlist, cnt);
  hipLaunchKernelGGL(k_pre1a, dim3(1600), dim3(256), 0, stream, x, pw, pb, g1w, hp1);
  hipLaunchKernelGGL((k_esed<16,4>), dim3(400), dim3(256), 0, stream, hp1, g1as, g1ad, es1, ed1);
  hipLaunchKernelGGL((k_gat_s<4, true>),  dim3(400), dim3(256), 0, stream, hp1, es1, ed1, nlist, cnt, g1b, x1);
  hipLaunchKernelGGL(k_pre2a, dim3(3200), dim3(256), 0, stream, x1, g2w, hp2);
  hipLaunchKernelGGL((k_esed<32,8>), dim3(400), dim3(256), 0, stream, hp2, g2as, g2ad, es2, ed2);
  hipLaunchKernelGGL((k_gat_s<8, false>), dim3(400), dim3(256), 0, stream, hp2, es2, ed2, nlist, cnt, g2b, h2);
  hipLaunchKernelGGL(k_trans2, dim3(NSEQ/4), dim3(512), 0, stream, h2, tw, (float*)d_out);
}

// Round 11
// 73.346 us; speedup vs baseline: 3.6000x; 1.2572x over previous
//
#include <hip/hip_runtime.h>

#define DEVINL __device__ __forceinline__

DEVINL float gelu_exact(float x){ return 0.5f * x * (1.0f + erff(x * 0.70710678118654752f)); }
DEVINL float lrelu02(float x){ return x >= 0.0f ? x : 0.2f * x; }

// B=4 S=16 N=400 -> 64 graph batches, 25600 node-rows, 1600 sequences
#define NN    400
#define NROWS 25600
#define NSEQ  1600

// ws byte offsets; peak 8,513,600 (h2 overlaps dead hp1/es1/ed1/x1)
#define OFF_NBR  0u
#define OFF_CNT  320000u
#define OFF_HP1  321600u
#define OFF_ES1  1960000u
#define OFF_ED1  2369600u
#define OFF_X1   2779200u
#define OFF_HP2  4417600u
#define OFF_ES2  7694400u
#define OFF_ED2  8104000u
#define OFF_H2   321600u     /* reuses hp1..x1 region (dead by gat2) */

// K1: sparse neighbor lists from cosine(adj_embed) > 0.5 (f64, ordered compaction)
__global__ __launch_bounds__(64) void k_nbr(const float* __restrict__ emb,
                                            unsigned short* __restrict__ nlist,
                                            int* __restrict__ cnt){
  const int i = blockIdx.x;
  const int lane = threadIdx.x;
  double ai[16];
  double si = 0.0;
  #pragma unroll
  for (int k = 0; k < 16; k++){ ai[k] = (double)emb[i*16 + k]; si += ai[k]*ai[k]; }
  const double rni = 1.0 / sqrt(fmax(si, 1e-12));
  int base = 0;
  #pragma unroll
  for (int t = 0; t < 7; t++){
    const int j = t*64 + lane;
    bool valid = false;
    if (j < NN){
      double sj = 0.0, dp = 0.0;
      #pragma unroll
      for (int k = 0; k < 16; k++){
        double bv = (double)emb[j*16 + k];
        sj += bv*bv; dp += ai[k]*bv;
      }
      double c = dp * rni / sqrt(fmax(sj, 1e-12));
      valid = (c > 0.5);
    }
    unsigned long long bal = __ballot(valid);
    int pre = __popcll(bal & ((1ull << lane) - 1ull));
    if (valid) nlist[i*NN + base + pre] = (unsigned short)j;
    base += (int)__popcll(bal);
  }
  if (lane == 0) cnt[i] = base;
}

// K2: fused proj + GAT1-pre (hp1, es1, ed1); one THREAD per row
__global__ __launch_bounds__(256) void k_pre1f(const float* __restrict__ x,
    const float* __restrict__ pw, const float* __restrict__ pb,
    const float* __restrict__ g1w, const float* __restrict__ as1,
    const float* __restrict__ ad1,
    float* __restrict__ hp1, float* __restrict__ es1, float* __restrict__ ed1){
  __shared__ float s_pw[48], s_pb[16], s_w[256], s_as[16], s_ad[16];
  int tid = threadIdx.x;
  if (tid < 48) s_pw[tid] = pw[tid];
  if (tid < 16){ s_pb[tid] = pb[tid]; s_as[tid] = as1[tid]; s_ad[tid] = ad1[tid]; }
  s_w[tid] = g1w[tid];
  __syncthreads();
  int row = blockIdx.x * 256 + tid;
  if (row >= NROWS) return;
  float x0 = x[row*3+0], x1v = x[row*3+1], x2 = x[row*3+2];
  float h0[16];
  #pragma unroll
  for (int c = 0; c < 16; c++)
    h0[c] = s_pb[c] + x0 * s_pw[c] + x1v * s_pw[16+c] + x2 * s_pw[32+c];
  float hp[16];
  #pragma unroll
  for (int c = 0; c < 16; c++){
    float a = 0.f;
    #pragma unroll
    for (int k = 0; k < 16; k++) a += h0[k] * s_w[k*16 + c];
    hp[c] = a;
  }
  float4* hout = (float4*)(hp1 + (size_t)row * 16);
  hout[0] = make_float4(hp[0],hp[1],hp[2],hp[3]);
  hout[1] = make_float4(hp[4],hp[5],hp[6],hp[7]);
  hout[2] = make_float4(hp[8],hp[9],hp[10],hp[11]);
  hout[3] = make_float4(hp[12],hp[13],hp[14],hp[15]);
  #pragma unroll
  for (int h = 0; h < 4; h++){
    float es = 0.f, ed = 0.f;
    #pragma unroll
    for (int d = 0; d < 4; d++){ es += hp[h*4+d]*s_as[h*4+d]; ed += hp[h*4+d]*s_ad[h*4+d]; }
    es1[row*4 + h] = es;
    ed1[row*4 + h] = ed;
  }
}

// K4: fused GAT2-pre (hp2, es2, ed2); one THREAD per row
__global__ __launch_bounds__(256) void k_pre2f(const float* __restrict__ x1,
    const float* __restrict__ g2w, const float* __restrict__ as2,
    const float* __restrict__ ad2,
    float* __restrict__ hp2, float* __restrict__ es2, float* __restrict__ ed2){
  __shared__ float s_w[512], s_as[32], s_ad[32];
  int tid = threadIdx.x;
  s_w[tid] = g2w[tid];
  s_w[tid + 256] = g2w[tid + 256];
  if (tid < 32){ s_as[tid] = as2[tid]; s_ad[tid] = ad2[tid]; }
  __syncthreads();
  int row = blockIdx.x * 256 + tid;
  if (row >= NROWS) return;
  const float4* xin = (const float4*)(x1 + (size_t)row * 16);
  float4 r0 = xin[0], r1 = xin[1], r2 = xin[2], r3 = xin[3];
  float xr[16] = {r0.x,r0.y,r0.z,r0.w, r1.x,r1.y,r1.z,r1.w,
                  r2.x,r2.y,r2.z,r2.w, r3.x,r3.y,r3.z,r3.w};
  float hp[32];
  #pragma unroll
  for (int c = 0; c < 32; c++){
    float a = 0.f;
    #pragma unroll
    for (int k = 0; k < 16; k++) a += xr[k] * s_w[k*32 + c];
    hp[c] = a;
  }
  float4* hout = (float4*)(hp2 + (size_t)row * 32);
  #pragma unroll
  for (int qd = 0; qd < 8; qd++)
    hout[qd] = make_float4(hp[qd*4],hp[qd*4+1],hp[qd*4+2],hp[qd*4+3]);
  #pragma unroll
  for (int h = 0; h < 4; h++){
    float es = 0.f, ed = 0.f;
    #pragma unroll
    for (int d = 0; d < 8; d++){ es += hp[h*8+d]*s_as[h*8+d]; ed += hp[h*8+d]*s_ad[h*8+d]; }
    es2[row*4 + h] = es;
    ed2[row*4 + h] = ed;
  }
}

// K3/K5: SPARSE GAT. One THREAD per (row, head). (unchanged from round 10)
template<int D, bool GELU>
__global__ __launch_bounds__(256) void k_gat_s(const float* __restrict__ hp,
    const float* __restrict__ es, const float* __restrict__ ed,
    const unsigned short* __restrict__ nlist, const int* __restrict__ cnt,
    const float* __restrict__ bias, float* __restrict__ outp){
  constexpr int F = 4 * D;
  int idx = blockIdx.x * 256 + threadIdx.x;
  if (idx >= NROWS * 4) return;
  const int row = idx >> 2, h = idx & 3;
  const int b = row / NN;
  const int i = row - b * NN;
  const int n = cnt[i];
  const unsigned short* nl = nlist + i * NN;
  const float* esb = es + (size_t)b * NN * 4;
  const float* hpb = hp + (size_t)b * NN * F;
  const float edh = ed[(size_t)row * 4 + h];
  float mx = -1e30f;
  for (int k0 = 0; k0 < n; k0 += 8){
    int jj[8]; float wv[8];
    #pragma unroll
    for (int u = 0; u < 8; u++){
      int kk = k0 + u;
      jj[u] = (int)nl[kk < n ? kk : n - 1];
      wv[u] = (kk < n) ? 1.f : 0.f;
    }
    #pragma unroll
    for (int u = 0; u < 8; u++){
      float v = esb[jj[u]*4 + h];
      mx = fmaxf(mx, wv[u] > 0.5f ? v : -1e30f);
    }
  }
  const float m = lrelu02(edh + mx);
  float den = 0.f;
  float acc[D];
  #pragma unroll
  for (int d = 0; d < D; d++) acc[d] = 0.f;
  for (int k0 = 0; k0 < n; k0 += 8){
    int jj[8]; float wv[8], ev[8];
    #pragma unroll
    for (int u = 0; u < 8; u++){
      int kk = k0 + u;
      jj[u] = (int)nl[kk < n ? kk : n - 1];
      wv[u] = (kk < n) ? 1.f : 0.f;
    }
    #pragma unroll
    for (int u = 0; u < 8; u++) ev[u] = esb[jj[u]*4 + h];
    #pragma unroll
    for (int u = 0; u < 8; u++){
      float pv = wv[u] * __expf(lrelu02(edh + ev[u]) - m);
      den += pv;
      const float4* vp = (const float4*)(hpb + (size_t)jj[u]*F + h*D);
      float4 v0 = vp[0];
      acc[0] += pv * v0.x; acc[1] += pv * v0.y;
      acc[2] += pv * v0.z; acc[3] += pv * v0.w;
      if (D == 8){
        float4 v1 = vp[1];
        acc[4] += pv * v1.x; acc[5] += pv * v1.y;
        acc[6] += pv * v1.z; acc[7] += pv * v1.w;
      }
    }
  }
  const float invd = 1.0f / den;
  float* op = outp + (size_t)row * F + h * D;
  #pragma unroll
  for (int d = 0; d < D; d++){
    float v = acc[d] * invd + bias[h*D + d];
    if (GELU) v = gelu_exact(v);
    op[d] = v;
  }
}

struct TW { const float* p[20]; };
// order: 0 wq,1 bq,2 wk,3 bk,4 wv,5 bv,6 wo,7 bo,8 ln1g,9 ln1b,
//        10 fw1,11 fb1,12 fw2,13 fb2,14 ln2g,15 ln2b,16 rw1,17 rb1,18 rw2,19 rb2

// K6 v3: ONE WAVE PER SEQUENCE. 256 thr = 4 waves/block, grid = NSEQ/4.
// Weights staged once (single barrier); main work is wave-synchronous
// (per-wave in-order LDS pipeline => ds_write->ds_read needs no barrier).
// Per-wave scratch: T/K/V stride-33 + S (Q -> A -> F2 stride-66) union.
__global__ __launch_bounds__(256) void k_trans3(const float* __restrict__ h2, TW tw,
                                                float* __restrict__ out){
  __shared__ float Wq[1024], Wk[1024], Wv[1024], Wo[1024];
  __shared__ float Fw1[2048], Fw2[2048], Rw1[512];
  __shared__ float Bq[32], Bk[32], Bv[32], Bo[32], L1g[32], L1b[32];
  __shared__ float Fb1[64], Fb2[32], L2g[32], L2b[32], Rb1v[16], Rw2[16];
  __shared__ float Rb2s[1];
  __shared__ float SCR[4][2640];   // per-wave: T 528 | K 528 | V 528 | S 1056
  const int tid = threadIdx.x;
  const int w = tid >> 6, lane = tid & 63;
  for (int i = tid; i < 1024; i += 256){
    Wq[i] = tw.p[0][i]; Wk[i] = tw.p[2][i]; Wv[i] = tw.p[4][i]; Wo[i] = tw.p[6][i];
  }
  for (int i = tid; i < 2048; i += 256){ Fw1[i] = tw.p[10][i]; Fw2[i] = tw.p[12][i]; }
  for (int i = tid; i < 512; i += 256) Rw1[i] = tw.p[16][i];
  if (tid < 32){
    Bq[tid] = tw.p[1][tid]; Bk[tid] = tw.p[3][tid]; Bv[tid] = tw.p[5][tid]; Bo[tid] = tw.p[7][tid];
    L1g[tid] = tw.p[8][tid]; L1b[tid] = tw.p[9][tid]; Fb2[tid] = tw.p[13][tid];
    L2g[tid] = tw.p[14][tid]; L2b[tid] = tw.p[15][tid];
  }
  if (tid < 64) Fb1[tid] = tw.p[11][tid];
  if (tid < 16){ Rb1v[tid] = tw.p[17][tid]; Rw2[tid] = tw.p[18][tid]; }
  if (tid == 0) Rb2s[0] = tw.p[19][0];
  __syncthreads();   // the only block barrier

  float* Tw = SCR[w];
  float* Kw = Tw + 528;
  float* Vw = Tw + 1056;
  float* Sw = Tw + 1584;
  const int p = blockIdx.x * 4 + w;
  const int s = lane >> 2, cg = lane & 3, ob = cg * 8;

  // load sequence tile into T (stride 33)
  {
    const float4* src = (const float4*)(h2 + (size_t)(p * 16 + s) * 32 + ob);
    float4 a0 = src[0], a1 = src[1];
    float* tr = Tw + s*33 + ob;
    tr[0]=a0.x; tr[1]=a0.y; tr[2]=a0.z; tr[3]=a0.w;
    tr[4]=a1.x; tr[5]=a1.y; tr[6]=a1.z; tr[7]=a1.w;
  }
  // QKV projections
  float q[8], kk[8], vv[8];
  #pragma unroll
  for (int u = 0; u < 8; u++){ q[u] = Bq[ob+u]; kk[u] = Bk[ob+u]; vv[u] = Bv[ob+u]; }
  for (int f = 0; f < 32; f++){
    float tv = Tw[s*33 + f];
    #pragma unroll
    for (int u = 0; u < 8; u++){
      q[u]  += tv * Wq[f*32 + ob + u];
      kk[u] += tv * Wk[f*32 + ob + u];
      vv[u] += tv * Wv[f*32 + ob + u];
    }
  }
  #pragma unroll
  for (int u = 0; u < 8; u++){
    Sw[s*33 + ob + u] = q[u];     // Q into S region
    Kw[s*33 + ob + u] = kk[u];
    Vw[s*33 + ob + u] = vv[u];
  }
  // attention: lane -> (h = lane>>5, i = (lane>>1)&15, half = lane&1)
  const int ai = (lane >> 1) & 15;
  const int hb = (lane >> 5) * 16 + (lane & 1) * 8;
  float qreg[8];
  #pragma unroll
  for (int u = 0; u < 8; u++) qreg[u] = Sw[ai*33 + hb + u];
  float sc[16];
  float mx = -1e30f;
  #pragma unroll
  for (int j = 0; j < 16; j++){
    float d = 0.f;
    #pragma unroll
    for (int u = 0; u < 8; u++) d += qreg[u] * Kw[j*33 + hb + u];
    d += __shfl_xor(d, 1);       // combine the two halves of the dk-dot
    d *= 0.25f;
    sc[j] = d;
    mx = fmaxf(mx, d);
  }
  float den = 0.f;
  #pragma unroll
  for (int j = 0; j < 16; j++){ sc[j] = __expf(sc[j] - mx); den += sc[j]; }
  const float ainv = 1.0f / den;
  float at[8];
  #pragma unroll
  for (int u = 0; u < 8; u++) at[u] = 0.f;
  #pragma unroll
  for (int j = 0; j < 16; j++){
    float al = sc[j];
    #pragma unroll
    for (int u = 0; u < 8; u++) at[u] += al * Vw[j*33 + hb + u];
  }
  #pragma unroll
  for (int u = 0; u < 8; u++) Sw[ai*33 + hb + u] = at[u] * ainv;  // A over Q
  // out-proj + residual + LN1 (back to (s,cg))
  float xr[8];
  #pragma unroll
  for (int u = 0; u < 8; u++) xr[u] = Bo[ob + u];
  for (int i2 = 0; i2 < 32; i2++){
    float av = Sw[s*33 + i2];
    #pragma unroll
    for (int u = 0; u < 8; u++) xr[u] += av * Wo[i2*32 + ob + u];
  }
  #pragma unroll
  for (int u = 0; u < 8; u++) xr[u] += Tw[s*33 + ob + u];
  float sm = 0.f, sq = 0.f;
  #pragma unroll
  for (int u = 0; u < 8; u++){ sm += xr[u]; sq += xr[u]*xr[u]; }
  sm += __shfl_xor(sm, 1); sq += __shfl_xor(sq, 1);
  sm += __shfl_xor(sm, 2); sq += __shfl_xor(sq, 2);
  {
    float mean = sm * (1.f/32.f);
    float var  = sq * (1.f/32.f) - mean*mean;
    float rinv = 1.0f / sqrtf(var + 1e-3f);
    #pragma unroll
    for (int u = 0; u < 8; u++)
      Tw[s*33 + ob + u] = (xr[u] - mean) * rinv * L1g[ob+u] + L1b[ob+u];
  }
  // FF1 -> F2 in S (stride 66; A dead)
  {
    const int cb = cg * 16;
    #pragma unroll
    for (int t = 0; t < 16; t++){
      int c = cb + t;
      float a = Fb1[c];
      for (int f = 0; f < 32; f++) a += Tw[s*33 + f] * Fw1[f*64 + c];
      Sw[s*66 + c] = gelu_exact(a);
    }
  }
  // FF2 + residual + LN2
  float y[8];
  #pragma unroll
  for (int u = 0; u < 8; u++) y[u] = Fb2[ob + u];
  for (int c = 0; c < 64; c++){
    float fv = Sw[s*66 + c];
    #pragma unroll
    for (int u = 0; u < 8; u++) y[u] += fv * Fw2[c*32 + ob + u];
  }
  #pragma unroll
  for (int u = 0; u < 8; u++) y[u] += Tw[s*33 + ob + u];
  sm = 0.f; sq = 0.f;
  #pragma unroll
  for (int u = 0; u < 8; u++){ sm += y[u]; sq += y[u]*y[u]; }
  sm += __shfl_xor(sm, 1); sq += __shfl_xor(sq, 1);
  sm += __shfl_xor(sm, 2); sq += __shfl_xor(sq, 2);
  float mean2 = sm * (1.f/32.f);
  float var2  = sq * (1.f/32.f) - mean2*mean2;
  float rinv2 = 1.0f / sqrtf(var2 + 1e-3f);
  // mean over the 16 tokens (butterfly over s bits: 4,8,16,32)
  float mv[8];
  #pragma unroll
  for (int u = 0; u < 8; u++){
    float v = (y[u] - mean2) * rinv2 * L2g[ob+u] + L2b[ob+u];
    v += __shfl_xor(v, 4);  v += __shfl_xor(v, 8);
    v += __shfl_xor(v, 16); v += __shfl_xor(v, 32);
    mv[u] = v * (1.f/16.f);
  }
  if (s == 0){
    #pragma unroll
    for (int u = 0; u < 8; u++) Tw[ob + u] = mv[u];   // M into T row 0
  }
  // readout (t = lane&15, redundant across 4 groups)
  const int t = lane & 15;
  float hid = Rb1v[t];
  for (int o2 = 0; o2 < 32; o2++) hid += Tw[o2] * Rw1[o2*16 + t];
  hid = gelu_exact(hid) * Rw2[t];
  hid += __shfl_xor(hid, 1); hid += __shfl_xor(hid, 2);
  hid += __shfl_xor(hid, 4); hid += __shfl_xor(hid, 8);
  if (lane == 0) out[p] = hid + Rb2s[0];
}

extern "C" void kernel_launch(void* const* d_in, const int* in_sizes, int n_in,
                              void* d_out, int out_size, void* d_ws, size_t ws_size,
                              hipStream_t stream){
  const float* x    = (const float*)d_in[0];
  const float* adj  = (const float*)d_in[1];
  const float* pw   = (const float*)d_in[2];
  const float* pb   = (const float*)d_in[3];
  const float* g1w  = (const float*)d_in[4];
  const float* g1as = (const float*)d_in[5];
  const float* g1ad = (const float*)d_in[6];
  const float* g1b  = (const float*)d_in[7];
  const float* g2w  = (const float*)d_in[8];
  const float* g2as = (const float*)d_in[9];
  const float* g2ad = (const float*)d_in[10];
  const float* g2b  = (const float*)d_in[11];

  char* ws = (char*)d_ws;
  unsigned short* nlist = (unsigned short*)(ws + OFF_NBR);
  int*   cnt = (int*)(ws + OFF_CNT);
  float* hp1 = (float*)(ws + OFF_HP1);
  float* es1 = (float*)(ws + OFF_ES1);
  float* ed1 = (float*)(ws + OFF_ED1);
  float* x1  = (float*)(ws + OFF_X1);
  float* hp2 = (float*)(ws + OFF_HP2);
  float* es2 = (float*)(ws + OFF_ES2);
  float* ed2 = (float*)(ws + OFF_ED2);
  float* h2  = (float*)(ws + OFF_H2);   // overlaps hp1..x1 (dead by gat2)

  TW tw;
  for (int t = 0; t < 20; t++) tw.p[t] = (const float*)d_in[12 + t];

  hipLaunchKernelGGL(k_nbr,   dim3(NN), dim3(64), 0, stream, adj, nlist, cnt);
  hipLaunchKernelGGL(k_pre1f, dim3(100), dim3(256), 0, stream, x, pw, pb, g1w, g1as, g1ad, hp1, es1, ed1);
  hipLaunchKernelGGL((k_gat_s<4, true>),  dim3(400), dim3(256), 0, stream, hp1, es1, ed1, nlist, cnt, g1b, x1);
  hipLaunchKernelGGL(k_pre2f, dim3(100), dim3(256), 0, stream, x1, g2w, g2as, g2ad, hp2, es2, ed2);
  hipLaunchKernelGGL((k_gat_s<8, false>), dim3(400), dim3(256), 0, stream, hp2, es2, ed2, nlist, cnt, g2b, h2);
  hipLaunchKernelGGL(k_trans3, dim3(NSEQ/4), dim3(256), 0, stream, h2, tw, (float*)d_out);
}